// Round 9
// baseline (161.336 us; speedup 1.0000x reference)
//
#include <hip/hip_runtime.h>
#include <hip/hip_bf16.h>
#include <math.h>

typedef __bf16 bf16x8 __attribute__((ext_vector_type(8)));
typedef float  f32x4  __attribute__((ext_vector_type(4)));

#define M_DIM 16384
#define N_DIM 512
#define K_DIM 512
#define TBL_N 1024

#define X_ELEMS ((long)M_DIM * K_DIM)
#define W_ELEMS ((long)N_DIM * K_DIM)
#define WS_NEED ((X_ELEMS + W_ELEMS) * 2)

// ---------------- kernel 1: fp32 -> bf16 pre-convert into d_ws ----------------
__global__ __launch_bounds__(256)
void convert_kernel(const float* __restrict__ x, const float* __restrict__ W,
                    __bf16* __restrict__ xb, __bf16* __restrict__ wb)
{
    const long XN8 = X_ELEMS / 8;
    const long T8  = XN8 + W_ELEMS / 8;
    for (long i = (long)blockIdx.x * 256 + threadIdx.x; i < T8;
         i += (long)gridDim.x * 256) {
        const float* src;
        __bf16* dst;
        if (i < XN8) { src = x + i * 8;          dst = xb + i * 8; }
        else         { src = W + (i - XN8) * 8;  dst = wb + (i - XN8) * 8; }
        float4 a = *(const float4*)src;
        float4 b = *(const float4*)(src + 4);
        bf16x8 r;
        r[0] = (__bf16)a.x; r[1] = (__bf16)a.y; r[2] = (__bf16)a.z; r[3] = (__bf16)a.w;
        r[4] = (__bf16)b.x; r[5] = (__bf16)b.y; r[6] = (__bf16)b.z; r[7] = (__bf16)b.w;
        *(bf16x8*)dst = r;
    }
}

__device__ inline void gl_lds16(const __bf16* g, __bf16* l) {
    __builtin_amdgcn_global_load_lds(
        (const __attribute__((address_space(1))) void*)g,
        (__attribute__((address_space(3))) void*)l, 16, 0, 0);
}

// ---------------- kernel 2: TRANSPOSED GEMM (A=W, B=x) + fused HH ----------------
// D row index <-> W-row (gn), D col <-> x-row (gm): each thread's 4 acc elems
// are 4 consecutive gn at fixed gm -> float4 epilogue stores (48 instrs vs 192).
// LDS double-buffered, ONE barrier per K-tile: tile k+1's DMA is issued before
// computing tile k, so the end-of-iteration barrier drains a DMA that has had
// the whole MFMA phase to complete.
__global__ __launch_bounds__(256, 2)
void gemm_hh_kernel(const __bf16* __restrict__ xb, const __bf16* __restrict__ wb,
                    const float* __restrict__ gNa_p, const float* __restrict__ gK_p,
                    const float* __restrict__ gL_p, float* __restrict__ out)
{
    __shared__ __bf16 sW[2 * 128 * 64];
    __shared__ __bf16 sX[2 * 128 * 64];
    __shared__ float  tbl[TBL_N + 1];

    const int tid = threadIdx.x;

    // XCD swizzle: each XCD owns 16 bm tiles (2 MB bf16 x = its L2)
    const int id   = blockIdx.x;            // 0..511
    const int xcd  = id & 7;
    const int slot = id >> 3;               // 0..63
    const int bm   = xcd * 16 + (slot >> 2);    // x-tile 0..127
    const int bn   = slot & 3;                  // W-tile 0..3

    const int wv   = tid >> 6;
    const int ln   = tid & 63;
    const int lr   = ln & 15;
    const int quad = ln >> 4;
    const int wN   = (wv & 1) * 64;     // W-row offset in tile
    const int wM   = (wv >> 1) * 64;    // x-row offset in tile

    // DMA source pattern (XOR chunk swizzle on global address; LDS dest fixed)
    const int rw  = ln >> 3;
    const int ch  = ln & 7;
    const int chx = (ch ^ rw) * 8;
    const __bf16* xSrc = xb + ((long)bm * 128 + 32 * wv + rw) * K_DIM + chx;
    const __bf16* wSrc = wb + ((long)bn * 128 + 32 * wv + rw) * K_DIM + chx;

    f32x4 acc[4][4] = {};   // [tW][tX]

    // ---- prime: issue tile-0 DMA, then build table (overlaps DMA latency) ----
    #pragma unroll
    for (int j = 0; j < 4; ++j) {
        gl_lds16(wSrc + (long)(8 * j) * K_DIM, sW + (32 * wv + 8 * j) * 64);
        gl_lds16(xSrc + (long)(8 * j) * K_DIM, sX + (32 * wv + 8 * j) * 64);
    }
    {
        const float gNa = *gNa_p, gK = *gK_p, gL = *gL_p;
        for (int i = tid; i <= TBL_N; i += 256) {
            const float V = -4.0f + (8.0f / TBL_N) * i;
            const float am = 0.1f * (V + 40.0f) / (1.0f - expf(-(V + 40.0f) * 0.1f));
            const float bm_ = 4.0f * expf(-(V + 65.0f) * (1.0f / 18.0f));
            const float ah = 0.07f * expf(-(V + 65.0f) * 0.05f);
            const float bh = 1.0f / (1.0f + expf(-(V + 35.0f) * 0.1f));
            const float an = 0.01f * (V + 55.0f) / (1.0f - expf(-(V + 55.0f) * 0.1f));
            const float bn_ = 0.125f * expf(-(V + 65.0f) * 0.0125f);
            const float m = 0.05f + 0.1f * (am * 0.95f - bm_ * 0.05f);
            const float h = 0.60f + 0.1f * (ah * 0.40f - bh * 0.60f);
            const float n = 0.32f + 0.1f * (an * 0.68f - bn_ * 0.32f);
            tbl[i] = gNa * m * m * m * h * (V - 50.0f)
                   + gK * (n * n) * (n * n) * (V + 77.0f)
                   + gL * (V + 54.4f) + V;
        }
    }
    __syncthreads();   // tile 0 resident

    for (int t = 0; t < 8; ++t) {
        const int cur = (t & 1) * 8192;
        const int nxt = 8192 - cur;
        if (t < 7) {
            const int kt = (t + 1) * 64;
            #pragma unroll
            for (int j = 0; j < 4; ++j) {
                gl_lds16(wSrc + (long)(8 * j) * K_DIM + kt, sW + nxt + (32 * wv + 8 * j) * 64);
                gl_lds16(xSrc + (long)(8 * j) * K_DIM + kt, sX + nxt + (32 * wv + 8 * j) * 64);
            }
        }
        #pragma unroll
        for (int kk = 0; kk < 2; ++kk) {
            bf16x8 aw[4], bx[4];
            const int cidx = quad + 4 * kk;
            const int sl   = (cidx ^ (lr & 7)) * 8;
            #pragma unroll
            for (int f = 0; f < 4; ++f) {
                aw[f] = *(const bf16x8*)(sW + cur + (wN + f * 16 + lr) * 64 + sl);
                bx[f] = *(const bf16x8*)(sX + cur + (wM + f * 16 + lr) * 64 + sl);
            }
            #pragma unroll
            for (int tw = 0; tw < 4; ++tw)
                #pragma unroll
                for (int tx = 0; tx < 4; ++tx)
                    acc[tw][tx] = __builtin_amdgcn_mfma_f32_16x16x32_bf16(
                        aw[tw], bx[tx], acc[tw][tx], 0, 0, 0);
        }
        __syncthreads();   // drains next-tile DMA (covered by MFMA phase) + LDS reuse
    }

    // ---- float4 epilogue: 4 consecutive gn per thread per frag ----
    float* outS = out;
    float* outV = out + (long)M_DIM * N_DIM;
    float* outW = out + 2L * M_DIM * N_DIM;

    #pragma unroll
    for (int tw = 0; tw < 4; ++tw) {
        const int gn4 = bn * 128 + wN + tw * 16 + quad * 4;   // 16B-aligned col base
        #pragma unroll
        for (int tx = 0; tx < 4; ++tx) {
            const long gm  = (long)bm * 128 + wM + tx * 16 + lr;
            const long idx = gm * N_DIM + gn4;
            f32x4 vS, vV, vW;
            #pragma unroll
            for (int i = 0; i < 4; ++i) {
                const float V = acc[tw][tx][i];
                float u = (V + 4.0f) * (TBL_N / 8.0f);
                u = fminf(fmaxf(u, 0.0f), (float)TBL_N - 0.001f);
                const int   iu = (int)u;
                const float f  = u - (float)iu;
                const float I_in = tbl[iu] + f * (tbl[iu + 1] - tbl[iu]);
                const float v_new = -65.0f + I_in * 0.005f;
                const float spike = (v_new >= -50.0f) ? 1.0f : 0.0f;
                vS[i] = spike;
                vW[i] = (0.5f * (v_new + 65.0f) + 0.1f * spike) * 0.001f;
                vV[i] = (spike > 0.5f) ? -65.0f : v_new;
            }
            *(f32x4*)(outS + idx) = vS;
            *(f32x4*)(outV + idx) = vV;
            *(f32x4*)(outW + idx) = vW;
        }
    }
}

// ---------------- fallback (R6 structure) if d_ws is too small ----------------
#define BMf 64
#define BNf 128
#define LDSTf 72
typedef __bf16 bf16x4 __attribute__((ext_vector_type(4)));
__global__ __launch_bounds__(256, 4)
void snn_fallback_kernel(const float* __restrict__ x, const float* __restrict__ W,
                         const float* __restrict__ gNa_p, const float* __restrict__ gK_p,
                         const float* __restrict__ gL_p, float* __restrict__ out)
{
    __shared__ __bf16 sA[BMf * LDSTf];
    __shared__ __bf16 sB[BNf * LDSTf];
    __shared__ float  tbl[TBL_N + 1];

    const int tid = threadIdx.x;
    const int id   = blockIdx.x;
    const int xcd  = id & 7;
    const int slot = id >> 3;
    const int bm   = xcd * 32 + (slot >> 2);
    const int bn   = slot & 3;

    const int c4 = (tid & 15) * 4;
    const int r0 = tid >> 4;
    const float* xBase = x + (long)(bm * BMf + r0) * K_DIM + c4;
    const float* wBase = W + (long)(bn * BNf + r0) * K_DIM + c4;

    const int wave = tid >> 6;
    const int lane = tid & 63;
    const int wM   = (wave & 1) * 32;
    const int wN   = (wave >> 1) * 64;
    const int lr   = lane & 15;
    const int quad = lane >> 4;

    f32x4 acc[2][4] = {};
    float4 pa[4], pb[8];
    #pragma unroll
    for (int rr = 0; rr < 4; ++rr) pa[rr] = *(const float4*)(xBase + (long)rr * 16 * K_DIM);
    #pragma unroll
    for (int rr = 0; rr < 8; ++rr) pb[rr] = *(const float4*)(wBase + (long)rr * 16 * K_DIM);

    {
        const float gNa = *gNa_p, gK = *gK_p, gL = *gL_p;
        for (int i = tid; i <= TBL_N; i += 256) {
            const float V = -4.0f + (8.0f / TBL_N) * i;
            const float am = 0.1f * (V + 40.0f) / (1.0f - expf(-(V + 40.0f) * 0.1f));
            const float bm_ = 4.0f * expf(-(V + 65.0f) * (1.0f / 18.0f));
            const float ah = 0.07f * expf(-(V + 65.0f) * 0.05f);
            const float bh = 1.0f / (1.0f + expf(-(V + 35.0f) * 0.1f));
            const float an = 0.01f * (V + 55.0f) / (1.0f - expf(-(V + 55.0f) * 0.1f));
            const float bn_ = 0.125f * expf(-(V + 65.0f) * 0.0125f);
            const float m = 0.05f + 0.1f * (am * 0.95f - bm_ * 0.05f);
            const float h = 0.60f + 0.1f * (ah * 0.40f - bh * 0.60f);
            const float n = 0.32f + 0.1f * (an * 0.68f - bn_ * 0.32f);
            tbl[i] = gNa * m * m * m * h * (V - 50.0f)
                   + gK * (n * n) * (n * n) * (V + 77.0f)
                   + gL * (V + 54.4f) + V;
        }
    }

    for (int kt = 0; kt < K_DIM; kt += 64) {
        const int ktn = (kt + 64 < K_DIM) ? kt + 64 : kt;
        const float* xp = xBase + ktn;
        const float* wp = wBase + ktn;
        #pragma unroll
        for (int rr = 0; rr < 4; ++rr) {
            float4 v = pa[rr];
            pa[rr] = *(const float4*)(xp + (long)rr * 16 * K_DIM);
            bf16x4 b = { (__bf16)v.x, (__bf16)v.y, (__bf16)v.z, (__bf16)v.w };
            *(bf16x4*)(&sA[(r0 + rr * 16) * LDSTf + c4]) = b;
        }
        #pragma unroll
        for (int rr = 0; rr < 8; ++rr) {
            float4 v = pb[rr];
            pb[rr] = *(const float4*)(wp + (long)rr * 16 * K_DIM);
            bf16x4 b = { (__bf16)v.x, (__bf16)v.y, (__bf16)v.z, (__bf16)v.w };
            *(bf16x4*)(&sB[(r0 + rr * 16) * LDSTf + c4]) = b;
        }
        __syncthreads();
        #pragma unroll
        for (int ks = 0; ks < 64; ks += 32) {
            bf16x8 af[2], bfr[4];
            #pragma unroll
            for (int t = 0; t < 2; ++t)
                af[t]  = *(const bf16x8*)(&sA[(wM + t * 16 + lr) * LDSTf + ks + quad * 8]);
            #pragma unroll
            for (int t = 0; t < 4; ++t)
                bfr[t] = *(const bf16x8*)(&sB[(wN + t * 16 + lr) * LDSTf + ks + quad * 8]);
            #pragma unroll
            for (int mt = 0; mt < 2; ++mt)
                #pragma unroll
                for (int nt = 0; nt < 4; ++nt)
                    acc[mt][nt] = __builtin_amdgcn_mfma_f32_16x16x32_bf16(
                        af[mt], bfr[nt], acc[mt][nt], 0, 0, 0);
        }
        __syncthreads();
    }

    float* outS = out;
    float* outV = out + (long)M_DIM * N_DIM;
    float* outW = out + 2L * M_DIM * N_DIM;
    #pragma unroll
    for (int mt = 0; mt < 2; ++mt) {
        #pragma unroll
        for (int i = 0; i < 4; ++i) {
            const long gm = (long)bm * BMf + wM + mt * 16 + quad * 4 + i;
            #pragma unroll
            for (int nt = 0; nt < 4; ++nt) {
                const int gn = bn * BNf + wN + nt * 16 + lr;
                const float V = acc[mt][nt][i];
                float u = (V + 4.0f) * (TBL_N / 8.0f);
                u = fminf(fmaxf(u, 0.0f), (float)TBL_N - 0.001f);
                const int   iu = (int)u;
                const float f  = u - (float)iu;
                const float I_in = tbl[iu] + f * (tbl[iu + 1] - tbl[iu]);
                const float v_new = -65.0f + I_in * 0.005f;
                const float spike = (v_new >= -50.0f) ? 1.0f : 0.0f;
                const float w_new = (0.5f * (v_new + 65.0f) + 0.1f * spike) * 0.001f;
                const float v_rs  = (spike > 0.5f) ? -65.0f : v_new;
                const long idx = gm * N_DIM + gn;
                outS[idx] = spike; outV[idx] = v_rs; outW[idx] = w_new;
            }
        }
    }
}

extern "C" void kernel_launch(void* const* d_in, const int* in_sizes, int n_in,
                              void* d_out, int out_size, void* d_ws, size_t ws_size,
                              hipStream_t stream) {
    const float* x   = (const float*)d_in[0];
    const float* W   = (const float*)d_in[1];
    const float* gNa = (const float*)d_in[2];
    const float* gK  = (const float*)d_in[3];
    const float* gL  = (const float*)d_in[4];
    float* out = (float*)d_out;

    if (ws_size >= (size_t)WS_NEED) {
        __bf16* xb = (__bf16*)d_ws;
        __bf16* wb = xb + X_ELEMS;
        hipLaunchKernelGGL(convert_kernel, dim3(1024), dim3(256), 0, stream, x, W, xb, wb);
        hipLaunchKernelGGL(gemm_hh_kernel, dim3(512), dim3(256), 0, stream,
                           xb, wb, gNa, gK, gL, out);
    } else {
        hipLaunchKernelGGL(snn_fallback_kernel, dim3(1024), dim3(256), 0, stream,
                           x, W, gNa, gK, gL, out);
    }
}

// Round 10
// 148.483 us; speedup vs baseline: 1.0866x; 1.0866x over previous
//
#include <hip/hip_runtime.h>
#include <hip/hip_bf16.h>
#include <math.h>

typedef __bf16 bf16x8 __attribute__((ext_vector_type(8)));
typedef float  f32x4  __attribute__((ext_vector_type(4)));

#define M_DIM 16384
#define N_DIM 512
#define K_DIM 512
#define TBL_N 1024

#define X_ELEMS ((long)M_DIM * K_DIM)
#define W_ELEMS ((long)N_DIM * K_DIM)
#define WS_NEED ((X_ELEMS + W_ELEMS) * 2)

// ---------------- kernel 1: fp32 -> bf16 pre-convert into d_ws ----------------
__global__ __launch_bounds__(256)
void convert_kernel(const float* __restrict__ x, const float* __restrict__ W,
                    __bf16* __restrict__ xb, __bf16* __restrict__ wb)
{
    const long XN8 = X_ELEMS / 8;
    const long T8  = XN8 + W_ELEMS / 8;
    for (long i = (long)blockIdx.x * 256 + threadIdx.x; i < T8;
         i += (long)gridDim.x * 256) {
        const float* src;
        __bf16* dst;
        if (i < XN8) { src = x + i * 8;          dst = xb + i * 8; }
        else         { src = W + (i - XN8) * 8;  dst = wb + (i - XN8) * 8; }
        float4 a = *(const float4*)src;
        float4 b = *(const float4*)(src + 4);
        bf16x8 r;
        r[0] = (__bf16)a.x; r[1] = (__bf16)a.y; r[2] = (__bf16)a.z; r[3] = (__bf16)a.w;
        r[4] = (__bf16)b.x; r[5] = (__bf16)b.y; r[6] = (__bf16)b.z; r[7] = (__bf16)b.w;
        *(bf16x8*)dst = r;
    }
}

__device__ inline void gl_lds16(const __bf16* g, __bf16* l) {
    __builtin_amdgcn_global_load_lds(
        (const __attribute__((address_space(1))) void*)g,
        (__attribute__((address_space(3))) void*)l, 16, 0, 0);
}

// ---------------- kernel 2: GEMM (A=W, B=x) + fused HH ----------------
// Tile 128m x 64n, grid 1024 = 4 blocks/CU (16 waves/CU to fill barrier
// drains). Single-buffered LDS, 2 barriers/K-tile (R8 structure — dbuf
// regressed in R9: compiler inserts vmcnt(0) before ds_read for DMA-alias
// safety). Swapped operands => thread's 4 acc regs are 4 consecutive gn
// => float4 epilogue stores (24 dwordx4 vs 192 dword).
__global__ __launch_bounds__(256, 4)
void gemm_hh_kernel(const __bf16* __restrict__ xb, const __bf16* __restrict__ wb,
                    const float* __restrict__ gNa_p, const float* __restrict__ gK_p,
                    const float* __restrict__ gL_p, float* __restrict__ out)
{
    __shared__ __bf16 sW[64 * 64];     // W-tile: 64 gn rows x 64 k
    __shared__ __bf16 sX[128 * 64];    // x-tile: 128 gm rows x 64 k
    __shared__ float  tbl[TBL_N + 1];

    const int tid = threadIdx.x;

    // XCD swizzle: each XCD owns 16 bm tiles (16*128 rows * 1 KB bf16 = 2 MB
    // of xb = its L2); consecutive slots sweep all 8 bn for one bm.
    const int id   = blockIdx.x;            // 0..1023
    const int xcd  = id & 7;
    const int slot = id >> 3;               // 0..127
    const int bm   = xcd * 16 + (slot >> 3);    // 0..127
    const int bn   = slot & 7;                  // 0..7

    const int wv   = tid >> 6;
    const int ln   = tid & 63;
    const int lr   = ln & 15;
    const int quad = ln >> 4;

    // DMA source pattern: lane covers row rw=ln>>3 of an 8-row group, 16B
    // chunk ch=ln&7; XOR swizzle applied on the GLOBAL address (LDS dest is
    // fixed wave-uniform-base + lane*16): LDS[r][c] holds global chunk c^(r&7).
    const int rw  = ln >> 3;
    const int ch  = ln & 7;
    const int chx = (ch ^ rw) * 8;
    const __bf16* wSrc = wb + ((long)bn * 64 + 16 * wv + rw) * K_DIM + chx;
    const __bf16* xSrc = xb + ((long)bm * 128 + 32 * wv + rw) * K_DIM + chx;

    // ---- prime tile-0 DMA (overlaps the table build) ----
    #pragma unroll
    for (int j = 0; j < 2; ++j)
        gl_lds16(wSrc + (long)(8 * j) * K_DIM, sW + (16 * wv + 8 * j) * 64);
    #pragma unroll
    for (int j = 0; j < 4; ++j)
        gl_lds16(xSrc + (long)(8 * j) * K_DIM, sX + (32 * wv + 8 * j) * 64);

    // ---- exact-HH I_in(V) table ----
    {
        const float gNa = *gNa_p, gK = *gK_p, gL = *gL_p;
        for (int i = tid; i <= TBL_N; i += 256) {
            const float V = -4.0f + (8.0f / TBL_N) * i;
            const float am = 0.1f * (V + 40.0f) / (1.0f - expf(-(V + 40.0f) * 0.1f));
            const float bm_ = 4.0f * expf(-(V + 65.0f) * (1.0f / 18.0f));
            const float ah = 0.07f * expf(-(V + 65.0f) * 0.05f);
            const float bh = 1.0f / (1.0f + expf(-(V + 35.0f) * 0.1f));
            const float an = 0.01f * (V + 55.0f) / (1.0f - expf(-(V + 55.0f) * 0.1f));
            const float bn_ = 0.125f * expf(-(V + 65.0f) * 0.0125f);
            const float m = 0.05f + 0.1f * (am * 0.95f - bm_ * 0.05f);
            const float h = 0.60f + 0.1f * (ah * 0.40f - bh * 0.60f);
            const float n = 0.32f + 0.1f * (an * 0.68f - bn_ * 0.32f);
            tbl[i] = gNa * m * m * m * h * (V - 50.0f)
                   + gK * (n * n) * (n * n) * (V + 77.0f)
                   + gL * (V + 54.4f) + V;
        }
    }
    __syncthreads();   // tile 0 resident

    f32x4 acc[4][2] = {};   // [gn frag f][gm frag g]

    for (int t = 0; t < 8; ++t) {
        #pragma unroll
        for (int kk = 0; kk < 2; ++kk) {
            const int cidx = quad + 4 * kk;
            const int sl   = (cidx ^ (lr & 7)) * 8;
            bf16x8 aw[4], bx[2];
            #pragma unroll
            for (int f = 0; f < 4; ++f)
                aw[f] = *(const bf16x8*)(sW + (f * 16 + lr) * 64 + sl);
            #pragma unroll
            for (int g = 0; g < 2; ++g)
                bx[g] = *(const bf16x8*)(sX + (32 * wv + g * 16 + lr) * 64 + sl);
            #pragma unroll
            for (int f = 0; f < 4; ++f)
                #pragma unroll
                for (int g = 0; g < 2; ++g)
                    acc[f][g] = __builtin_amdgcn_mfma_f32_16x16x32_bf16(
                        aw[f], bx[g], acc[f][g], 0, 0, 0);
        }
        if (t < 7) {
            __syncthreads();   // all reads of tile t done
            const int kt = (t + 1) * 64;
            #pragma unroll
            for (int j = 0; j < 2; ++j)
                gl_lds16(wSrc + (long)(8 * j) * K_DIM + kt, sW + (16 * wv + 8 * j) * 64);
            #pragma unroll
            for (int j = 0; j < 4; ++j)
                gl_lds16(xSrc + (long)(8 * j) * K_DIM + kt, sX + (32 * wv + 8 * j) * 64);
            __syncthreads();   // drain DMA (filled by other resident blocks)
        }
    }

    // ---- float4 epilogue: 4 consecutive gn per thread per frag ----
    float* outS = out;
    float* outV = out + (long)M_DIM * N_DIM;
    float* outW = out + 2L * M_DIM * N_DIM;

    #pragma unroll
    for (int f = 0; f < 4; ++f) {
        const int gn4 = bn * 64 + f * 16 + quad * 4;
        #pragma unroll
        for (int g = 0; g < 2; ++g) {
            const long gm  = (long)bm * 128 + 32 * wv + g * 16 + lr;
            const long idx = gm * N_DIM + gn4;
            f32x4 vS, vV, vW;
            #pragma unroll
            for (int i = 0; i < 4; ++i) {
                const float V = acc[f][g][i];
                float u = (V + 4.0f) * (TBL_N / 8.0f);
                u = fminf(fmaxf(u, 0.0f), (float)TBL_N - 0.001f);
                const int   iu = (int)u;
                const float fr = u - (float)iu;
                const float I_in = tbl[iu] + fr * (tbl[iu + 1] - tbl[iu]);
                const float v_new = -65.0f + I_in * 0.005f;
                const float spike = (v_new >= -50.0f) ? 1.0f : 0.0f;
                vS[i] = spike;
                vW[i] = (0.5f * (v_new + 65.0f) + 0.1f * spike) * 0.001f;
                vV[i] = (spike > 0.5f) ? -65.0f : v_new;
            }
            *(f32x4*)(outS + idx) = vS;
            *(f32x4*)(outV + idx) = vV;
            *(f32x4*)(outW + idx) = vW;
        }
    }
}

// ---------------- fallback (R6 structure) if d_ws is too small ----------------
#define BMf 64
#define BNf 128
#define LDSTf 72
typedef __bf16 bf16x4 __attribute__((ext_vector_type(4)));
__global__ __launch_bounds__(256, 4)
void snn_fallback_kernel(const float* __restrict__ x, const float* __restrict__ W,
                         const float* __restrict__ gNa_p, const float* __restrict__ gK_p,
                         const float* __restrict__ gL_p, float* __restrict__ out)
{
    __shared__ __bf16 sA[BMf * LDSTf];
    __shared__ __bf16 sB[BNf * LDSTf];
    __shared__ float  tbl[TBL_N + 1];

    const int tid = threadIdx.x;
    const int id   = blockIdx.x;
    const int xcd  = id & 7;
    const int slot = id >> 3;
    const int bm   = xcd * 32 + (slot >> 2);
    const int bn   = slot & 3;

    const int c4 = (tid & 15) * 4;
    const int r0 = tid >> 4;
    const float* xBase = x + (long)(bm * BMf + r0) * K_DIM + c4;
    const float* wBase = W + (long)(bn * BNf + r0) * K_DIM + c4;

    const int wave = tid >> 6;
    const int lane = tid & 63;
    const int wM   = (wave & 1) * 32;
    const int wN   = (wave >> 1) * 64;
    const int lr   = lane & 15;
    const int quad = lane >> 4;

    f32x4 acc[2][4] = {};
    float4 pa[4], pb[8];
    #pragma unroll
    for (int rr = 0; rr < 4; ++rr) pa[rr] = *(const float4*)(xBase + (long)rr * 16 * K_DIM);
    #pragma unroll
    for (int rr = 0; rr < 8; ++rr) pb[rr] = *(const float4*)(wBase + (long)rr * 16 * K_DIM);

    {
        const float gNa = *gNa_p, gK = *gK_p, gL = *gL_p;
        for (int i = tid; i <= TBL_N; i += 256) {
            const float V = -4.0f + (8.0f / TBL_N) * i;
            const float am = 0.1f * (V + 40.0f) / (1.0f - expf(-(V + 40.0f) * 0.1f));
            const float bm_ = 4.0f * expf(-(V + 65.0f) * (1.0f / 18.0f));
            const float ah = 0.07f * expf(-(V + 65.0f) * 0.05f);
            const float bh = 1.0f / (1.0f + expf(-(V + 35.0f) * 0.1f));
            const float an = 0.01f * (V + 55.0f) / (1.0f - expf(-(V + 55.0f) * 0.1f));
            const float bn_ = 0.125f * expf(-(V + 65.0f) * 0.0125f);
            const float m = 0.05f + 0.1f * (am * 0.95f - bm_ * 0.05f);
            const float h = 0.60f + 0.1f * (ah * 0.40f - bh * 0.60f);
            const float n = 0.32f + 0.1f * (an * 0.68f - bn_ * 0.32f);
            tbl[i] = gNa * m * m * m * h * (V - 50.0f)
                   + gK * (n * n) * (n * n) * (V + 77.0f)
                   + gL * (V + 54.4f) + V;
        }
    }

    for (int kt = 0; kt < K_DIM; kt += 64) {
        const int ktn = (kt + 64 < K_DIM) ? kt + 64 : kt;
        const float* xp = xBase + ktn;
        const float* wp = wBase + ktn;
        #pragma unroll
        for (int rr = 0; rr < 4; ++rr) {
            float4 v = pa[rr];
            pa[rr] = *(const float4*)(xp + (long)rr * 16 * K_DIM);
            bf16x4 b = { (__bf16)v.x, (__bf16)v.y, (__bf16)v.z, (__bf16)v.w };
            *(bf16x4*)(&sA[(r0 + rr * 16) * LDSTf + c4]) = b;
        }
        #pragma unroll
        for (int rr = 0; rr < 8; ++rr) {
            float4 v = pb[rr];
            pb[rr] = *(const float4*)(wp + (long)rr * 16 * K_DIM);
            bf16x4 b = { (__bf16)v.x, (__bf16)v.y, (__bf16)v.z, (__bf16)v.w };
            *(bf16x4*)(&sB[(r0 + rr * 16) * LDSTf + c4]) = b;
        }
        __syncthreads();
        #pragma unroll
        for (int ks = 0; ks < 64; ks += 32) {
            bf16x8 af[2], bfr[4];
            #pragma unroll
            for (int t = 0; t < 2; ++t)
                af[t]  = *(const bf16x8*)(&sA[(wM + t * 16 + lr) * LDSTf + ks + quad * 8]);
            #pragma unroll
            for (int t = 0; t < 4; ++t)
                bfr[t] = *(const bf16x8*)(&sB[(wN + t * 16 + lr) * LDSTf + ks + quad * 8]);
            #pragma unroll
            for (int mt = 0; mt < 2; ++mt)
                #pragma unroll
                for (int nt = 0; nt < 4; ++nt)
                    acc[mt][nt] = __builtin_amdgcn_mfma_f32_16x16x32_bf16(
                        af[mt], bfr[nt], acc[mt][nt], 0, 0, 0);
        }
        __syncthreads();
    }

    float* outS = out;
    float* outV = out + (long)M_DIM * N_DIM;
    float* outW = out + 2L * M_DIM * N_DIM;
    #pragma unroll
    for (int mt = 0; mt < 2; ++mt) {
        #pragma unroll
        for (int i = 0; i < 4; ++i) {
            const long gm = (long)bm * BMf + wM + mt * 16 + quad * 4 + i;
            #pragma unroll
            for (int nt = 0; nt < 4; ++nt) {
                const int gn = bn * BNf + wN + nt * 16 + lr;
                const float V = acc[mt][nt][i];
                float u = (V + 4.0f) * (TBL_N / 8.0f);
                u = fminf(fmaxf(u, 0.0f), (float)TBL_N - 0.001f);
                const int   iu = (int)u;
                const float f  = u - (float)iu;
                const float I_in = tbl[iu] + f * (tbl[iu + 1] - tbl[iu]);
                const float v_new = -65.0f + I_in * 0.005f;
                const float spike = (v_new >= -50.0f) ? 1.0f : 0.0f;
                const float w_new = (0.5f * (v_new + 65.0f) + 0.1f * spike) * 0.001f;
                const float v_rs  = (spike > 0.5f) ? -65.0f : v_new;
                const long idx = gm * N_DIM + gn;
                outS[idx] = spike; outV[idx] = v_rs; outW[idx] = w_new;
            }
        }
    }
}

extern "C" void kernel_launch(void* const* d_in, const int* in_sizes, int n_in,
                              void* d_out, int out_size, void* d_ws, size_t ws_size,
                              hipStream_t stream) {
    const float* x   = (const float*)d_in[0];
    const float* W   = (const float*)d_in[1];
    const float* gNa = (const float*)d_in[2];
    const float* gK  = (const float*)d_in[3];
    const float* gL  = (const float*)d_in[4];
    float* out = (float*)d_out;

    if (ws_size >= (size_t)WS_NEED) {
        __bf16* xb = (__bf16*)d_ws;
        __bf16* wb = xb + X_ELEMS;
        hipLaunchKernelGGL(convert_kernel, dim3(1024), dim3(256), 0, stream, x, W, xb, wb);
        hipLaunchKernelGGL(gemm_hh_kernel, dim3(1024), dim3(256), 0, stream,
                           xb, wb, gNa, gK, gL, out);
    } else {
        hipLaunchKernelGGL(snn_fallback_kernel, dim3(1024), dim3(256), 0, stream,
                           x, W, gNa, gK, gL, out);
    }
}